// Round 2
// baseline (90.557 us; speedup 1.0000x reference)
//
#include <hip/hip_runtime.h>

#define WAVE 64

// Kernel 1: find segment boundaries of the sorted ray_id array.
__global__ __launch_bounds__(256) void seg_bounds_kernel(
    const int* __restrict__ ray_id, int n,
    int* __restrict__ seg_start, int* __restrict__ seg_end)
{
    int i = blockIdx.x * blockDim.x + threadIdx.x;
    if (i >= n) return;
    int rid = ray_id[i];
    if (i == 0 || ray_id[i - 1] != rid) seg_start[rid] = i;
    if (i == n - 1 || ray_id[i + 1] != rid) seg_end[rid] = i + 1;
}

// Kernel 2: one wave (64 lanes) per ray. Direct multiplicative scan —
// no log/exp (mathematically identical to exp(cumsum(log(clip)))).
__global__ __launch_bounds__(256) void ray_kernel(
    const float* __restrict__ alpha,
    const float* __restrict__ values3d,
    const float* __restrict__ values1d,
    const float* __restrict__ weights,
    const float* __restrict__ sample_values,
    const int*   __restrict__ seg_start,
    const int*   __restrict__ seg_end,
    float* __restrict__ out_T,    // [N]
    float* __restrict__ out_bg,   // [R]
    float* __restrict__ out_i3,   // [R,3]
    float* __restrict__ out_i1,   // [R]
    float* __restrict__ out_spr,  // [R,3]
    float* __restrict__ out_sps,  // [N,3]
    int R)
{
    int lane = threadIdx.x & (WAVE - 1);
    int wave = threadIdx.x >> 6;
    int r = blockIdx.x * (blockDim.x >> 6) + wave;
    if (r >= R) return;

    int s0 = seg_start[r];
    int s1 = seg_end[r];

    float c = 1.0f;  // running product carry across 64-wide chunks
    float i3x = 0.f, i3y = 0.f, i3z = 0.f, i1 = 0.f;
    float sx = 0.f, sy = 0.f, sz = 0.f;

    for (int base = s0; base < s1; base += WAVE) {
        int i = base + lane;
        bool act = i < s1;
        float om = 1.0f;  // multiplicative identity for inactive lanes
        if (act) {
            om = 1.0f - alpha[i];
            om = fminf(fmaxf(om, 1e-7f), 1.0f);
        }
        // 64-lane inclusive multiplicative scan
        float incl = om;
        #pragma unroll
        for (int d = 1; d < WAVE; d <<= 1) {
            float o = __shfl_up(incl, d, WAVE);
            if (lane >= d) incl *= o;
        }
        // exclusive via shift-by-1
        float excl = __shfl_up(incl, 1, WAVE);
        if (lane == 0) excl = 1.0f;
        if (act) {
            out_T[i] = c * excl;
            float w = weights[i];
            i3x += values3d[3 * i + 0] * w;
            i3y += values3d[3 * i + 1] * w;
            i3z += values3d[3 * i + 2] * w;
            i1  += values1d[i] * w;
            sx  += sample_values[3 * i + 0];
            sy  += sample_values[3 * i + 1];
            sz  += sample_values[3 * i + 2];
        }
        c *= __shfl(incl, WAVE - 1, WAVE);  // inactive lanes contributed 1
    }

    // wave all-reduce (every lane ends with the total)
    #pragma unroll
    for (int d = 1; d < WAVE; d <<= 1) {
        i3x += __shfl_xor(i3x, d, WAVE);
        i3y += __shfl_xor(i3y, d, WAVE);
        i3z += __shfl_xor(i3z, d, WAVE);
        i1  += __shfl_xor(i1,  d, WAVE);
        sx  += __shfl_xor(sx,  d, WAVE);
        sy  += __shfl_xor(sy,  d, WAVE);
        sz  += __shfl_xor(sz,  d, WAVE);
    }

    if (lane == 0) {
        out_bg[r] = c;
        out_i3[3 * r + 0] = i3x;
        out_i3[3 * r + 1] = i3y;
        out_i3[3 * r + 2] = i3z;
        out_i1[r] = i1;
        out_spr[3 * r + 0] = sx;
        out_spr[3 * r + 1] = sy;
        out_spr[3 * r + 2] = sz;
    }

    // broadcast sum_per_ray back over the segment (fused sum_per_sample)
    for (int base = s0; base < s1; base += WAVE) {
        int i = base + lane;
        if (i < s1) {
            out_sps[3 * i + 0] = sx;
            out_sps[3 * i + 1] = sy;
            out_sps[3 * i + 2] = sz;
        }
    }
}

extern "C" void kernel_launch(void* const* d_in, const int* in_sizes, int n_in,
                              void* d_out, int out_size, void* d_ws, size_t ws_size,
                              hipStream_t stream) {
    const float* alpha = (const float*)d_in[0];
    const float* v3    = (const float*)d_in[1];
    const float* v1    = (const float*)d_in[2];
    const float* w     = (const float*)d_in[3];
    const float* sv    = (const float*)d_in[4];
    const int*   rid   = (const int*)d_in[5];

    int N = in_sizes[0];
    int R = (out_size - 4 * N) / 8;  // out = N + R + 3R + R + 3R + 3N

    int* seg_start = (int*)d_ws;
    int* seg_end   = seg_start + R;
    hipMemsetAsync(d_ws, 0, (size_t)2 * R * sizeof(int), stream);

    float* out     = (float*)d_out;
    float* out_T   = out;
    float* out_bg  = out + N;
    float* out_i3  = out_bg + R;
    float* out_i1  = out_i3 + 3 * (size_t)R;
    float* out_spr = out_i1 + R;
    float* out_sps = out_spr + 3 * (size_t)R;

    seg_bounds_kernel<<<(N + 255) / 256, 256, 0, stream>>>(rid, N, seg_start, seg_end);

    int wavesPerBlock = 4;  // 256 threads
    int blocks = (R + wavesPerBlock - 1) / wavesPerBlock;
    ray_kernel<<<blocks, 256, 0, stream>>>(alpha, v3, v1, w, sv, seg_start, seg_end,
                                           out_T, out_bg, out_i3, out_i1, out_spr,
                                           out_sps, R);
}

// Round 4
// 57.424 us; speedup vs baseline: 1.5770x; 1.5770x over previous
//
#include <hip/hip_runtime.h>

// ---------- cross-lane helpers (compile-time patterns) ----------
template<int CTRL>
__device__ __forceinline__ float dpp1(float x) {
    // DPP move with old = 1.0f (multiplicative identity), bound_ctrl=false:
    // invalid-source lanes (shift past row edge) receive 1.0f.
    return __int_as_float(__builtin_amdgcn_update_dpp(
        0x3f800000, __float_as_int(x), CTRL, 0xF, 0xF, false));
}
template<int PAT>
__device__ __forceinline__ float swz(float x) {
    return __int_as_float(__builtin_amdgcn_ds_swizzle(__float_as_int(x), PAT));
}
// xor-butterfly all-reduce within each 16-lane group
#define BFLY16(v) do { \
    v += swz<0x041F>(v); \
    v += swz<0x081F>(v); \
    v += swz<0x101F>(v); \
    v += swz<0x201F>(v); } while (0)

// Kernel 1: segment bounds of the sorted ray_id array.
__global__ __launch_bounds__(256) void seg_bounds_kernel(
    const int* __restrict__ ray_id, int n,
    int* __restrict__ seg_start, int* __restrict__ seg_end)
{
    int i = blockIdx.x * blockDim.x + threadIdx.x;
    if (i >= n) return;
    int rid = ray_id[i];
    if (i == 0 || ray_id[i - 1] != rid) seg_start[rid] = i;
    if (i == n - 1 || ray_id[i + 1] != rid) seg_end[rid] = i + 1;
}

// Kernel 2: 16 lanes per ray, 4 samples per lane (aligned float4 tiles),
// 4 rays per wave. DPP scan within the 16-lane row; ds_swizzle butterflies
// for the 7 segment sums.
__global__ __launch_bounds__(256) void ray_kernel(
    const float* __restrict__ alpha,
    const float* __restrict__ values3d,
    const float* __restrict__ values1d,
    const float* __restrict__ weights,
    const float* __restrict__ sample_values,
    const int*   __restrict__ seg_start,
    const int*   __restrict__ seg_end,
    float* __restrict__ out_T,    // [N]
    float* __restrict__ out_bg,   // [R]
    float* __restrict__ out_i3,   // [R,3]
    float* __restrict__ out_i1,   // [R]
    float* __restrict__ out_spr,  // [R,3]
    float* __restrict__ out_sps,  // [N,3]
    int R)
{
    const int lane = threadIdx.x & 63;
    const int wid  = threadIdx.x >> 6;
    const int j    = lane & 15;              // lane within 16-lane group
    const int g    = lane >> 4;              // group (ray slot) 0..3
    const int r    = (blockIdx.x * 4 + wid) * 4 + g;
    const bool ray_ok = (r < R);
    const int rc = ray_ok ? r : 0;

    int s0 = seg_start[rc];
    int s1 = seg_end[rc];
    if (!ray_ok) { s0 = 0; s1 = 0; }

    float c = 1.0f;                          // running product carry
    float i3x = 0.f, i3y = 0.f, i3z = 0.f, i1 = 0.f;
    float sx = 0.f, sy = 0.f, sz = 0.f;

    const int base0 = s0 & ~3;               // align tile grid to float4

    for (int base = base0; base < s1; base += 64) {
        const int a = base + 4 * j;          // this lane's aligned 4-sample slot
        // A lane participates iff its slot starts before s1. All lanes have
        // a >= base0 >= s0-3; with a%4==0, a<s1<=N, N%4==0 => a+3 <= N-1.
        const bool tile_ok = (a < s1);
        const int  al = tile_ok ? a : base0; // branch-free clamp to a valid,
                                             // 16B-aligned in-segment address
        // element ownership: k = al+e is a real sample of this ray
        const bool w0 = tile_ok & (a + 0 >= s0);
        const bool w1 = tile_ok & (a + 1 >= s0) & (a + 1 < s1);
        const bool w2 = tile_ok & (a + 2 >= s0) & (a + 2 < s1);
        const bool w3 = tile_ok & (a + 3 < s1);

        const float4 av = *(const float4*)(alpha + al);
        float o0 = fminf(fmaxf(1.0f - av.x, 1e-7f), 1.0f); if (!w0) o0 = 1.0f;
        float o1 = fminf(fmaxf(1.0f - av.y, 1e-7f), 1.0f); if (!w1) o1 = 1.0f;
        float o2 = fminf(fmaxf(1.0f - av.z, 1e-7f), 1.0f); if (!w2) o2 = 1.0f;
        float o3 = fminf(fmaxf(1.0f - av.w, 1e-7f), 1.0f); if (!w3) o3 = 1.0f;

        const float p01  = o0 * o1;
        const float p012 = p01 * o2;
        float p = p012 * o3;                 // lane-local product

        // inclusive multiplicative scan across the 16-lane row (DPP)
        p *= dpp1<0x111>(p);                 // row_shr:1
        p *= dpp1<0x112>(p);                 // row_shr:2
        p *= dpp1<0x114>(p);                 // row_shr:4
        p *= dpp1<0x118>(p);                 // row_shr:8
        const float gincl = p;
        const float gexcl = dpp1<0x111>(gincl);  // lane j=0 gets 1.0

        const float cg = c * gexcl;
        const float t0 = cg;
        const float t1 = cg * o0;
        const float t2 = cg * p01;
        const float t3 = cg * p012;

        if (w0 & w1 & w2 & w3) {
            *(float4*)(out_T + a) = make_float4(t0, t1, t2, t3);
        } else {
            if (w0) out_T[a + 0] = t0;
            if (w1) out_T[a + 1] = t1;
            if (w2) out_T[a + 2] = t2;
            if (w3) out_T[a + 3] = t3;
        }

        // masked weights / indicator
        const float4 wv = *(const float4*)(weights + al);
        const float W0 = w0 ? wv.x : 0.f;
        const float W1 = w1 ? wv.y : 0.f;
        const float W2 = w2 ? wv.z : 0.f;
        const float W3 = w3 ? wv.w : 0.f;
        const float M0 = w0 ? 1.f : 0.f;
        const float M1 = w1 ? 1.f : 0.f;
        const float M2 = w2 ? 1.f : 0.f;
        const float M3 = w3 ? 1.f : 0.f;

        const float4 v1v = *(const float4*)(values1d + al);
        i1 += v1v.x * W0 + v1v.y * W1 + v1v.z * W2 + v1v.w * W3;

        const float4 b0 = *(const float4*)(values3d + 3 * al);
        const float4 b1 = *(const float4*)(values3d + 3 * al + 4);
        const float4 b2 = *(const float4*)(values3d + 3 * al + 8);
        i3x += b0.x * W0 + b0.w * W1 + b1.z * W2 + b2.y * W3;
        i3y += b0.y * W0 + b1.x * W1 + b1.w * W2 + b2.z * W3;
        i3z += b0.z * W0 + b1.y * W1 + b2.x * W2 + b2.w * W3;

        const float4 q0 = *(const float4*)(sample_values + 3 * al);
        const float4 q1 = *(const float4*)(sample_values + 3 * al + 4);
        const float4 q2 = *(const float4*)(sample_values + 3 * al + 8);
        sx += q0.x * M0 + q0.w * M1 + q1.z * M2 + q2.y * M3;
        sy += q0.y * M0 + q1.x * M1 + q1.w * M2 + q2.z * M3;
        sz += q0.z * M0 + q1.y * M1 + q2.x * M2 + q2.w * M3;

        // carry: chunk total lives in lane 15 of the group
        c *= swz<0x1F0>(gincl);              // bcast group-lane-15
    }

    // 7-value all-reduce within each 16-lane group
    BFLY16(i3x); BFLY16(i3y); BFLY16(i3z); BFLY16(i1);
    BFLY16(sx);  BFLY16(sy);  BFLY16(sz);

    if (ray_ok && j == 0) {
        out_bg[r] = c;
        out_i3[3 * r + 0] = i3x;
        out_i3[3 * r + 1] = i3y;
        out_i3[3 * r + 2] = i3z;
        out_i1[r] = i1;
        out_spr[3 * r + 0] = sx;
        out_spr[3 * r + 1] = sy;
        out_spr[3 * r + 2] = sz;
    }

    // pass 2: broadcast sum_per_ray over the segment (stores fully masked)
    for (int base = base0; base < s1; base += 64) {
        const int a = base + 4 * j;
        const bool tile_ok = (a < s1);
        const bool w0 = tile_ok & (a + 0 >= s0);
        const bool w1 = tile_ok & (a + 1 >= s0) & (a + 1 < s1);
        const bool w2 = tile_ok & (a + 2 >= s0) & (a + 2 < s1);
        const bool w3 = tile_ok & (a + 3 < s1);
        if (w0 & w1 & w2 & w3) {
            *(float4*)(out_sps + 3 * a)     = make_float4(sx, sy, sz, sx);
            *(float4*)(out_sps + 3 * a + 4) = make_float4(sy, sz, sx, sy);
            *(float4*)(out_sps + 3 * a + 8) = make_float4(sz, sx, sy, sz);
        } else {
            if (w0) { out_sps[3*a+0] = sx; out_sps[3*a+1]  = sy; out_sps[3*a+2]  = sz; }
            if (w1) { out_sps[3*a+3] = sx; out_sps[3*a+4]  = sy; out_sps[3*a+5]  = sz; }
            if (w2) { out_sps[3*a+6] = sx; out_sps[3*a+7]  = sy; out_sps[3*a+8]  = sz; }
            if (w3) { out_sps[3*a+9] = sx; out_sps[3*a+10] = sy; out_sps[3*a+11] = sz; }
        }
    }
}

extern "C" void kernel_launch(void* const* d_in, const int* in_sizes, int n_in,
                              void* d_out, int out_size, void* d_ws, size_t ws_size,
                              hipStream_t stream) {
    const float* alpha = (const float*)d_in[0];
    const float* v3    = (const float*)d_in[1];
    const float* v1    = (const float*)d_in[2];
    const float* w     = (const float*)d_in[3];
    const float* sv    = (const float*)d_in[4];
    const int*   rid   = (const int*)d_in[5];

    int N = in_sizes[0];
    int R = (out_size - 4 * N) / 8;  // out = N + R + 3R + R + 3R + 3N

    int* seg_start = (int*)d_ws;
    int* seg_end   = seg_start + R;
    hipMemsetAsync(d_ws, 0, (size_t)2 * R * sizeof(int), stream);

    float* out     = (float*)d_out;
    float* out_T   = out;
    float* out_bg  = out + N;
    float* out_i3  = out_bg + R;
    float* out_i1  = out_i3 + 3 * (size_t)R;
    float* out_spr = out_i1 + R;
    float* out_sps = out_spr + 3 * (size_t)R;

    seg_bounds_kernel<<<(N + 255) / 256, 256, 0, stream>>>(rid, N, seg_start, seg_end);

    // 4 waves/block, 4 rays/wave -> 16 rays per block
    int blocks = (R + 15) / 16;
    ray_kernel<<<blocks, 256, 0, stream>>>(alpha, v3, v1, w, sv, seg_start, seg_end,
                                           out_T, out_bg, out_i3, out_i1, out_spr,
                                           out_sps, R);
}